// Round 5
// baseline (7193.368 us; speedup 1.0000x reference)
//
#include <hip/hip_runtime.h>
#include <cstdint>
#include <cstddef>

// ---------------------------------------------------------------------------
// LSTM  B=64, T=1024, D=H=512.
//   * xcvt: x_seq fp32 -> fp16 in ws (one-time).
//   * lstm_rec: persistent, 256 WGs = 8 batch-groups x 32 column-groups,
//     batch-group == physical XCD (runtime XCC_ID + slot counter; 96KB LDS
//     pad forces 1 WG/CU so pigeonhole gives exactly 32 WGs/XCD).
//   R8: evidence R5(agent)==R7(L2 flags) in time => transport fine, chain
//   taxed by (a) slow-path HBM ack serialized before flag, (b) sleep+agent
//   probes inside the spin, (c) 2.27e8 LDS bank-conflict cycles from weight
//   reads. Fixes:
//     * publish order: fast payload(sc0) -> vmcnt(0) [L2 ack only] -> fast
//       flag(sc0); THEN slow mirror payload -> vmcnt(0) -> slow flag
//       (insurance kept, moved off the critical path).
//     * consumer: tight sc0 flag spin (no s_sleep); agent fallback probe
//       every 32nd miss only (deadlock escape, ~never taken per R6 FETCH).
//     * weights Wh/Wx in REGISTERS (wb/xb, 128 VGPR) — R4-vs-R5 A/B showed
//       regs faster (conflicts 9.2e7 vs 2.27e8); no Wls/Xls LDS reads.
// ---------------------------------------------------------------------------

typedef _Float16 half8  __attribute__((ext_vector_type(8)));
typedef float    float4v __attribute__((ext_vector_type(4)));
typedef unsigned uint4v  __attribute__((ext_vector_type(4)));

__device__ __forceinline__ float sigm(float x) { return 1.f / (1.f + __expf(-x)); }
__device__ __forceinline__ float tanh_f(float x) { return 2.f / (1.f + __expf(-2.f * x)) - 1.f; }

// ws byte-offset map (all < 1 MB; XH at 1 MB):
//   fast payload [2][8][8192B]  @ 0        (sc0 / XCD-L2 path)
//   fast flags   [2][8][128B]   @ 131072
//   slot ctrs    [8 u32]        @ 139264
//   slow payload [2][8][8192B]  @ 262144   (agent / L3 fallback path)
//   slow flags   [2][8][128B]   @ 393216
#define FAST_FLAG  131072
#define SLOT_CTR   139264
#define SLOW_OFF   262144

// ----------------------------- x fp32 -> fp16 ------------------------------
__global__ __launch_bounds__(256) void xcvt(const float* __restrict__ X,
                                            _Float16* __restrict__ XH) {
    size_t i = ((size_t)blockIdx.x * 256 + threadIdx.x) * 8;
    float4 a = *(const float4*)(X + i);
    float4 b = *(const float4*)(X + i + 4);
    half8 v;
    v[0] = (_Float16)a.x; v[1] = (_Float16)a.y; v[2] = (_Float16)a.z; v[3] = (_Float16)a.w;
    v[4] = (_Float16)b.x; v[5] = (_Float16)b.y; v[6] = (_Float16)b.z; v[7] = (_Float16)b.w;
    *(half8*)(XH + i) = v;
}

// ------------------------------- recurrence --------------------------------
__global__ __launch_bounds__(256, 1) void lstm_rec(
    const float* __restrict__ Whf, const float* __restrict__ Whi,
    const float* __restrict__ Whg, const float* __restrict__ Who,
    const float* __restrict__ Wxf, const float* __restrict__ Wxi,
    const float* __restrict__ Wxg, const float* __restrict__ Wxo,
    const float* __restrict__ bxf, const float* __restrict__ bxi,
    const float* __restrict__ bxg, const float* __restrict__ bxo,
    const float* __restrict__ bhf, const float* __restrict__ bhi,
    const float* __restrict__ bhg, const float* __restrict__ bho,
    const _Float16* __restrict__ XH,   // [64][1024][512] fp16
    char* __restrict__ wsb,            // exchange area (see map above)
    float* __restrict__ out)           // [64][512] fp32
{
    const int tid  = threadIdx.x;
    const int w    = tid >> 6;
    const int lane = tid & 63;
    const int l15  = lane & 15;
    const int quad = lane >> 4;
    const int m    = l15 & 7;

    // 96KB static LDS pad: forces 1 WG/CU (XCD pigeonhole depends on it).
    __shared__ char smem[98304];
    _Float16 (*hls)[520] = (_Float16 (*)[520])smem;          // [8][520] fp16
    float    (*gs)[65]   = (float (*)[65])(smem + 8448);     // [8][65] f32
    __shared__ unsigned slot_sh;

    // ---- runtime XCD self-organization: g = physical XCD, c = slot ----
    unsigned xcd;
    asm volatile("s_getreg_b32 %0, hwreg(HW_REG_XCC_ID)" : "=s"(xcd));
    xcd &= 7;
    if (tid == 0) {
        unsigned* ctr = (unsigned*)(wsb + SLOT_CTR);
        slot_sh = __hip_atomic_fetch_add(&ctr[xcd], 1u, __ATOMIC_RELAXED,
                                         __HIP_MEMORY_SCOPE_AGENT);
    }
    __syncthreads();
    const int g = (int)xcd;
    const int c = (int)(slot_sh & 31);

    // ---- loop-invariant weight fragments in REGISTERS (wave = gate seg) ----
    const float* Whp = (w == 0) ? Whf : (w == 1) ? Whi : (w == 2) ? Whg : Who;
    const float* Wxp = (w == 0) ? Wxf : (w == 1) ? Wxi : (w == 2) ? Wxg : Wxo;
    const float* wrow = Whp + (size_t)(c * 16 + l15) * 512 + quad * 8;
    const float* xrw  = Wxp + (size_t)(c * 16 + l15) * 512 + quad * 8;
    half8 wb[16], xb[16];
#pragma unroll
    for (int kk = 0; kk < 16; kk++) {
        float4 a0 = *(const float4*)(wrow + kk * 32);
        float4 a1 = *(const float4*)(wrow + kk * 32 + 4);
        float4 b0 = *(const float4*)(xrw + kk * 32);
        float4 b1 = *(const float4*)(xrw + kk * 32 + 4);
        half8 vw = {(_Float16)a0.x, (_Float16)a0.y, (_Float16)a0.z, (_Float16)a0.w,
                    (_Float16)a1.x, (_Float16)a1.y, (_Float16)a1.z, (_Float16)a1.w};
        half8 vx = {(_Float16)b0.x, (_Float16)b0.y, (_Float16)b0.z, (_Float16)b0.w,
                    (_Float16)b1.x, (_Float16)b1.y, (_Float16)b1.z, (_Float16)b1.w};
        wb[kk] = vw;
        xb[kk] = vx;
    }

    // ---- elementwise role (wave 0): fused biases ----
    const int erow = tid >> 3;
    const int ep   = tid & 7;
    float bs[8] = {0.f};
    if (tid < 64) {
        int u0 = c * 16 + 2 * ep, u1 = u0 + 1;
        bs[0] = bxf[u0] + bhf[u0];  bs[4] = bxf[u1] + bhf[u1];
        bs[1] = bxi[u0] + bhi[u0];  bs[5] = bxi[u1] + bhi[u1];
        bs[2] = bxg[u0] + bhg[u0];  bs[6] = bxg[u1] + bhg[u1];
        bs[3] = bxo[u0] + bho[u0];  bs[7] = bxo[u1] + bho[u1];
    }
    float c0s = 0.f, c1s = 0.f;

    // payload staging role: thread reads 32B of the group's 8KB h payload
    const int crow = tid >> 5;          // 0..7
    const int ccol = (tid & 31) << 4;   // elem offset 0..496

    // h_0 = 0: stage locally, skip the t=0 poll entirely.
    {
        uint4v z = {0u, 0u, 0u, 0u};
        *(uint4v*)&hls[crow][ccol]     = z;
        *(uint4v*)&hls[crow][ccol + 8] = z;
    }
    __syncthreads();

    // ---- x-projection shadow: acc_x for step 0 (pure-reg MFMA) ----
    const size_t xrow = (size_t)(g * 8 + m) * 1024 * 512 + (size_t)quad * 8;
    half8 xf[16];
#pragma unroll
    for (int kk = 0; kk < 16; kk++) xf[kk] = *(const half8*)(XH + xrow + kk * 32);
    float4v accx = {0.f, 0.f, 0.f, 0.f};
#pragma unroll
    for (int kk = 0; kk < 16; kk++)
        accx = __builtin_amdgcn_mfma_f32_16x16x32_f16(xf[kk], xb[kk], accx, 0, 0, 0);

    for (int t = 0; t < 1024; t++) {
        // ---- issue x loads for t+1 FIRST; spin's vmcnt(0) absorbs them ----
        {
            int tn = (t < 1023) ? (t + 1) : 0;
            const _Float16* xp = XH + xrow + (size_t)tn * 512;
#pragma unroll
            for (int kk = 0; kk < 16; kk++) xf[kk] = *(const half8*)(xp + kk * 32);
        }

        // ---- flag spin + single payload read (t=0: hls pre-staged) ----
        if (t > 0) {
            const unsigned tv = (unsigned)t;
            const char* fb = wsb + FAST_FLAG + (size_t)(t & 1) * 1024
                           + g * 128 + ((lane & 7) << 4);
            const unsigned* sb = (const unsigned*)(fb + SLOW_OFF);
            bool slow = false;
            int miss = 0;
            for (;;) {
                uint4v fv;
                asm volatile("global_load_dwordx4 %0, %1, off sc0\n\t"
                             "s_waitcnt vmcnt(0)"
                             : "=&v"(fv) : "v"(fb) : "memory");
                if (__all(fv[0] == tv && fv[1] == tv &&
                          fv[2] == tv && fv[3] == tv)) break;
                if (((++miss) & 31) == 31) {  // rare anti-deadlock probe
                    unsigned s0 = __hip_atomic_load(sb + 0, __ATOMIC_RELAXED,
                                                    __HIP_MEMORY_SCOPE_AGENT);
                    unsigned s1 = __hip_atomic_load(sb + 1, __ATOMIC_RELAXED,
                                                    __HIP_MEMORY_SCOPE_AGENT);
                    unsigned s2 = __hip_atomic_load(sb + 2, __ATOMIC_RELAXED,
                                                    __HIP_MEMORY_SCOPE_AGENT);
                    unsigned s3 = __hip_atomic_load(sb + 3, __ATOMIC_RELAXED,
                                                    __HIP_MEMORY_SCOPE_AGENT);
                    if (__all(s0 == tv && s1 == tv && s2 == tv && s3 == tv)) {
                        slow = true; break;
                    }
                }
            }
            const size_t poff = (size_t)(t & 1) * 65536 + (size_t)g * 8192
                              + (size_t)tid * 32;
            uint4v p0, p1;
            if (!slow) {
                const char* pp = wsb + poff;
                asm volatile("global_load_dwordx4 %0, %2, off sc0\n\t"
                             "global_load_dwordx4 %1, %2, off offset:16 sc0\n\t"
                             "s_waitcnt vmcnt(0)"
                             : "=&v"(p0), "=&v"(p1) : "v"(pp) : "memory");
            } else {
                const unsigned long long* pp =
                    (const unsigned long long*)(wsb + SLOW_OFF + poff);
                unsigned long long q0 = __hip_atomic_load(pp + 0, __ATOMIC_RELAXED,
                                                          __HIP_MEMORY_SCOPE_AGENT);
                unsigned long long q1 = __hip_atomic_load(pp + 1, __ATOMIC_RELAXED,
                                                          __HIP_MEMORY_SCOPE_AGENT);
                unsigned long long q2 = __hip_atomic_load(pp + 2, __ATOMIC_RELAXED,
                                                          __HIP_MEMORY_SCOPE_AGENT);
                unsigned long long q3 = __hip_atomic_load(pp + 3, __ATOMIC_RELAXED,
                                                          __HIP_MEMORY_SCOPE_AGENT);
                p0[0] = (unsigned)q0; p0[1] = (unsigned)(q0 >> 32);
                p0[2] = (unsigned)q1; p0[3] = (unsigned)(q1 >> 32);
                p1[0] = (unsigned)q2; p1[1] = (unsigned)(q2 >> 32);
                p1[2] = (unsigned)q3; p1[3] = (unsigned)(q3 >> 32);
            }
            *(uint4v*)&hls[crow][ccol]     = p0;
            *(uint4v*)&hls[crow][ccol + 8] = p1;
        }

        // barrier 1: hls staged (ds ops drained; vmcnt NOT drained)
        asm volatile("s_waitcnt lgkmcnt(0)" ::: "memory");
        __builtin_amdgcn_s_barrier();
        __builtin_amdgcn_sched_barrier(0);

        // ---- h-GEMM: acc = acc_x + h_t @ Wh_slice^T (A from LDS, B regs) ----
        float4v acca = accx;
        float4v accb = {0.f, 0.f, 0.f, 0.f};
#pragma unroll
        for (int kk = 0; kk < 16; kk += 2) {
            half8 a0 = *(const half8*)&hls[m][kk * 32 + quad * 8];
            half8 a1 = *(const half8*)&hls[m][(kk + 1) * 32 + quad * 8];
            acca = __builtin_amdgcn_mfma_f32_16x16x32_f16(a0, wb[kk],     acca, 0, 0, 0);
            accb = __builtin_amdgcn_mfma_f32_16x16x32_f16(a1, wb[kk + 1], accb, 0, 0, 0);
        }

        if (quad < 2) {
#pragma unroll
            for (int r = 0; r < 4; r++)
                gs[quad * 4 + r][w * 16 + l15] = acca[r] + accb[r];
        }
        // barrier 2: gs ready
        asm volatile("s_waitcnt lgkmcnt(0)" ::: "memory");
        __builtin_amdgcn_s_barrier();
        __builtin_amdgcn_sched_barrier(0);

        // ---- elementwise LSTM update + ordered publish (wave 0 only) ----
        if (tid < 64) {
            float pf0 = gs[erow][2 * ep]      + bs[0];
            float pi0 = gs[erow][2 * ep + 16] + bs[1];
            float pg0 = gs[erow][2 * ep + 32] + bs[2];
            float po0 = gs[erow][2 * ep + 48] + bs[3];
            float pf1 = gs[erow][2 * ep + 1]  + bs[4];
            float pi1 = gs[erow][2 * ep + 17] + bs[5];
            float pg1 = gs[erow][2 * ep + 33] + bs[6];
            float po1 = gs[erow][2 * ep + 49] + bs[7];
            c0s = sigm(pf0) * c0s + sigm(pi0) * tanh_f(pg0);
            c1s = sigm(pf1) * c1s + sigm(pi1) * tanh_f(pg1);
            float hn0 = sigm(po0) * tanh_f(c0s);
            float hn1 = sigm(po1) * tanh_f(c1s);
            union { _Float16 f; unsigned short u; } cv0, cv1;
            cv0.f = (_Float16)hn0; cv1.f = (_Float16)hn1;
            unsigned pv = (unsigned)cv0.u | ((unsigned)cv1.u << 16);
            size_t poff = (size_t)((t + 1) & 1) * 65536 + (size_t)g * 8192
                        + (size_t)erow * 1024 + (size_t)(c * 16 + 2 * ep) * 2;
            char* fp = wsb + poff;
            unsigned fvv = (unsigned)(t + 1);
            char* ff = wsb + FAST_FLAG + (size_t)((t + 1) & 1) * 1024
                     + g * 128 + c * 4;
            // CRITICAL PATH: fast payload -> L2 ack -> fast flag.
            asm volatile("global_store_dword %0, %1, off sc0"
                         :: "v"(fp), "v"(pv) : "memory");
            asm volatile("s_waitcnt vmcnt(0)" ::: "memory");
            if (tid == 0)
                asm volatile("global_store_dword %0, %1, off sc0"
                             :: "v"(ff), "v"(fvv) : "memory");
            // OFF-CHAIN insurance: agent mirror, ordered among themselves.
            __hip_atomic_store((unsigned*)(fp + SLOW_OFF), pv, __ATOMIC_RELAXED,
                               __HIP_MEMORY_SCOPE_AGENT);
            asm volatile("s_waitcnt vmcnt(0)" ::: "memory");
            if (tid == 0)
                __hip_atomic_store((unsigned*)(ff + SLOW_OFF), fvv,
                                   __ATOMIC_RELAXED, __HIP_MEMORY_SCOPE_AGENT);
            if (t == 1023) {
                size_t ob = (size_t)(g * 8 + erow) * 512 + c * 16 + 2 * ep;
                out[ob]     = hn0;
                out[ob + 1] = hn1;
            }
        }

        // ---- x-GEMM tail for t+1: pure-register (xf loaded at loop top) ----
        float4v ax = {0.f, 0.f, 0.f, 0.f};
#pragma unroll
        for (int kk = 0; kk < 16; kk++)
            ax = __builtin_amdgcn_mfma_f32_16x16x32_f16(xf[kk], xb[kk], ax, 0, 0, 0);
        accx = ax;
    }
}

// ------------------------------- launcher ----------------------------------
extern "C" void kernel_launch(void* const* d_in, const int* in_sizes, int n_in,
                              void* d_out, int out_size, void* d_ws, size_t ws_size,
                              hipStream_t stream) {
    const float* X   = (const float*)d_in[0];
    const float* Whf = (const float*)d_in[1];  const float* bhf = (const float*)d_in[2];
    const float* Wxf = (const float*)d_in[3];  const float* bxf = (const float*)d_in[4];
    const float* Whi = (const float*)d_in[5];  const float* bhi = (const float*)d_in[6];
    const float* Wxi = (const float*)d_in[7];  const float* bxi = (const float*)d_in[8];
    const float* Whg = (const float*)d_in[9];  const float* bhg = (const float*)d_in[10];
    const float* Wxg = (const float*)d_in[11]; const float* bxg = (const float*)d_in[12];
    const float* Who = (const float*)d_in[13]; const float* bho = (const float*)d_in[14];
    const float* Wxo = (const float*)d_in[15]; const float* bxo = (const float*)d_in[16];

    if (ws_size < (size_t)68157440) return;  // need 65 MiB

    char* ws = (char*)d_ws;
    _Float16* XH = (_Float16*)(ws + (1 << 20));
    (void)in_sizes; (void)n_in; (void)out_size;

    hipMemsetAsync(d_ws, 0, 786432, stream);   // payloads + flags + ctrs
    xcvt<<<16384, 256, 0, stream>>>(X, XH);
    lstm_rec<<<256, 256, 0, stream>>>(Whf, Whi, Whg, Who, Wxf, Wxi, Wxg, Wxo,
                                      bxf, bxi, bxg, bxo, bhf, bhi, bhg, bho,
                                      XH, ws, (float*)d_out);
}

// Round 6
// 4018.661 us; speedup vs baseline: 1.7900x; 1.7900x over previous
//
#include <hip/hip_runtime.h>
#include <cstdint>
#include <cstddef>

// ---------------------------------------------------------------------------
// LSTM  B=64, T=1024, D=H=512.
//   * xcvt: x_seq fp32 -> fp16 in ws (one-time).
//   * lstm_rec: persistent, 256 WGs = 8 batch-groups x 32 column-groups.
//     WG (g,c): batch rows g*8..g*8+7, hidden units c*16..c*16+15.
//     Wh & Wx slices LDS-resident fp16 (133 KB, 1 WG/CU).
//     R3: SELF-SYNCHRONIZING TAGGED h — each h element is a u32
//     (step_tag<<16 | fp16). Producer publishes fire-and-forget (no vmcnt
//     ack, no flags). Consumer's poll IS the data load: whole WG
//     cooperatively spin-loads the group's tagged h once (per-lane spin,
//     64B/lane), stages payload into LDS, all waves read A-fragments from
//     LDS. Collapses ~4 serial L3 round trips/step to ~1.5 and cuts L3
//     h-read traffic 8x. Double-buffer + monotone tags make overwrite safe:
//     a WG writes tag t+1 only after observing ALL tags t, which implies
//     every peer finished reading tags t-1 from that buffer.
//   R9: EXACT REVERT to this verified 4018.8us structure. Session rounds
//     R4-R8 (reg-weights, raw barriers, XCD-L2 exchange, flag protocols)
//     all regressed; re-anchoring to separate code from container drift.
// ---------------------------------------------------------------------------

typedef _Float16 half8  __attribute__((ext_vector_type(8)));
typedef _Float16 half4v __attribute__((ext_vector_type(4)));
typedef float    float4v __attribute__((ext_vector_type(4)));

__device__ __forceinline__ float sigm(float x) { return 1.f / (1.f + __expf(-x)); }
__device__ __forceinline__ float tanh_f(float x) { return 2.f / (1.f + __expf(-2.f * x)) - 1.f; }

// ----------------------------- x fp32 -> fp16 ------------------------------
__global__ __launch_bounds__(256) void xcvt(const float* __restrict__ X,
                                            _Float16* __restrict__ XH) {
    size_t i = ((size_t)blockIdx.x * 256 + threadIdx.x) * 8;
    float4 a = *(const float4*)(X + i);
    float4 b = *(const float4*)(X + i + 4);
    half8 v;
    v[0] = (_Float16)a.x; v[1] = (_Float16)a.y; v[2] = (_Float16)a.z; v[3] = (_Float16)a.w;
    v[4] = (_Float16)b.x; v[5] = (_Float16)b.y; v[6] = (_Float16)b.z; v[7] = (_Float16)b.w;
    *(half8*)(XH + i) = v;
}

// ------------------------------- recurrence --------------------------------
__global__ __launch_bounds__(256, 1) void lstm_rec(
    const float* __restrict__ Whf, const float* __restrict__ Whi,
    const float* __restrict__ Whg, const float* __restrict__ Who,
    const float* __restrict__ Wxf, const float* __restrict__ Wxi,
    const float* __restrict__ Wxg, const float* __restrict__ Wxo,
    const float* __restrict__ bxf, const float* __restrict__ bxi,
    const float* __restrict__ bxg, const float* __restrict__ bxo,
    const float* __restrict__ bhf, const float* __restrict__ bhi,
    const float* __restrict__ bhg, const float* __restrict__ bho,
    const _Float16* __restrict__ XH,        // [64][1024][512] fp16
    unsigned long long* __restrict__ hws,   // tagged h [2][8][8][256] u64, zeroed
    float* __restrict__ out)                // [64][512] fp32
{
    const int blk  = blockIdx.x;
    const int g    = blk & 7;    // batch group (one XCD under round-robin)
    const int c    = blk >> 3;   // column group 0..31
    const int tid  = threadIdx.x;
    const int w    = tid >> 6;   // wave 0..3 -> gate-col tile w*16..w*16+15
    const int lane = tid & 63;
    const int l15  = lane & 15;
    const int quad = lane >> 4;
    const int m    = l15 & 7;    // batch row within group (rows 8..15 dup 0..7)

    __shared__ _Float16 Wls[64][520];  // Wh slice, rows = [f16|i16|g16|o16]
    __shared__ _Float16 Xls[64][520];  // Wx slice, same layout
    __shared__ _Float16 hls[8][520];   // staged h_t payload [row][512 units]
    __shared__ float    gs[8][65];     // gate preacts [row][gatecol]

    // ---- one-time: weight slices -> LDS fp16 ----
    const float* WhSeg[4] = {Whf, Whi, Whg, Who};
    const float* WxSeg[4] = {Wxf, Wxi, Wxg, Wxo};
    for (int e = tid * 4; e < 64 * 512; e += 1024) {
        int row = e >> 9, col = e & 511;
        int seg = row >> 4;
        int srow = c * 16 + (row & 15);
        float4 vh = *(const float4*)(WhSeg[seg] + (size_t)srow * 512 + col);
        float4 vx = *(const float4*)(WxSeg[seg] + (size_t)srow * 512 + col);
        half4v th = {(_Float16)vh.x, (_Float16)vh.y, (_Float16)vh.z, (_Float16)vh.w};
        half4v tx = {(_Float16)vx.x, (_Float16)vx.y, (_Float16)vx.z, (_Float16)vx.w};
        *(half4v*)&Wls[row][col] = th;
        *(half4v*)&Xls[row][col] = tx;
    }
    __syncthreads();

    // ---- elementwise role: wave 0 only, 64 threads x (1 row, 2 units) ----
    const int erow = tid >> 3;        // 0..7  (valid for tid<64)
    const int ep   = tid & 7;         // unit pair 0..7 -> units 2ep, 2ep+1
    float bs[8] = {0.f};              // f0,i0,g0,o0,f1,i1,g1,o1
    if (tid < 64) {
        int u0 = c * 16 + 2 * ep, u1 = u0 + 1;
        bs[0] = bxf[u0] + bhf[u0];  bs[4] = bxf[u1] + bhf[u1];
        bs[1] = bxi[u0] + bhi[u0];  bs[5] = bxi[u1] + bhi[u1];
        bs[2] = bxg[u0] + bhg[u0];  bs[6] = bxg[u1] + bhg[u1];
        bs[3] = bxo[u0] + bho[u0];  bs[7] = bxo[u1] + bho[u1];
    }
    float c0s = 0.f, c1s = 0.f;

    // consumer staging role: lane loads 16 tagged u32 (8 u64) of group h
    const int crow = tid >> 5;          // 0..7
    const int ccol = (tid & 31) << 4;   // 0..496

    // ---- x-projection shadow: acc_x for step 0 ----
    const size_t xrow = (size_t)(g * 8 + m) * 1024 * 512 + (size_t)quad * 8;
    half8 xf[16];
#pragma unroll
    for (int kk = 0; kk < 16; kk++) xf[kk] = *(const half8*)(XH + xrow + kk * 32);
    float4v accx = {0.f, 0.f, 0.f, 0.f};
#pragma unroll
    for (int kk = 0; kk < 16; kk++) {
        half8 b = *(const half8*)&Xls[w * 16 + l15][kk * 32 + quad * 8];
        accx = __builtin_amdgcn_mfma_f32_16x16x32_f16(xf[kk], b, accx, 0, 0, 0);
    }

    for (int t = 0; t < 1024; t++) {
        // ---- cooperative tagged spin-load of h_t -> LDS (poll IS the load)
        {
            const unsigned long long* hsrc = hws + (size_t)(t & 1) * 16384
                                           + (size_t)g * 2048 + (size_t)tid * 8;
            const unsigned long long T =
                ((unsigned long long)(unsigned)t << 16) |
                ((unsigned long long)(unsigned)t << 48);
            unsigned long long q[8];
            for (;;) {
                unsigned long long bad = 0;
#pragma unroll
                for (int j = 0; j < 8; j++)
                    q[j] = __hip_atomic_load(hsrc + j, __ATOMIC_RELAXED,
                                             __HIP_MEMORY_SCOPE_AGENT);
#pragma unroll
                for (int j = 0; j < 8; j++)
                    bad |= (q[j] ^ T) & 0xFFFF0000FFFF0000ULL;
                if (!bad) break;
            }
            unsigned int* hd = (unsigned int*)&hls[crow][ccol];
#pragma unroll
            for (int j = 0; j < 8; j++)
                hd[j] = (unsigned int)(q[j] & 0xFFFF) |
                        (((unsigned int)(q[j] >> 32)) << 16);
        }
        __syncthreads();

        // ---- h-GEMM: acc = acc_x + h_t @ Wh_slice^T (A-frags from LDS) ----
        float4v acca = accx;
        float4v accb = {0.f, 0.f, 0.f, 0.f};
#pragma unroll
        for (int kk = 0; kk < 16; kk += 2) {
            half8 a0 = *(const half8*)&hls[m][kk * 32 + quad * 8];
            half8 a1 = *(const half8*)&hls[m][(kk + 1) * 32 + quad * 8];
            half8 b0 = *(const half8*)&Wls[w * 16 + l15][kk * 32 + quad * 8];
            half8 b1 = *(const half8*)&Wls[w * 16 + l15][(kk + 1) * 32 + quad * 8];
            acca = __builtin_amdgcn_mfma_f32_16x16x32_f16(a0, b0, acca, 0, 0, 0);
            accb = __builtin_amdgcn_mfma_f32_16x16x32_f16(a1, b1, accb, 0, 0, 0);
        }

        // ---- gate preacts -> LDS (rows 0..7 live in quads 0,1) ----
        if (quad < 2) {
#pragma unroll
            for (int r = 0; r < 4; r++)
                gs[quad * 4 + r][w * 16 + l15] = acca[r] + accb[r];
        }
        __syncthreads();

        // ---- elementwise LSTM update + tagged publish (wave 0 only) ----
        if (tid < 64) {
            float pf0 = gs[erow][2 * ep]      + bs[0];
            float pi0 = gs[erow][2 * ep + 16] + bs[1];
            float pg0 = gs[erow][2 * ep + 32] + bs[2];
            float po0 = gs[erow][2 * ep + 48] + bs[3];
            float pf1 = gs[erow][2 * ep + 1]  + bs[4];
            float pi1 = gs[erow][2 * ep + 17] + bs[5];
            float pg1 = gs[erow][2 * ep + 33] + bs[6];
            float po1 = gs[erow][2 * ep + 49] + bs[7];
            c0s = sigm(pf0) * c0s + sigm(pi0) * tanh_f(pg0);
            c1s = sigm(pf1) * c1s + sigm(pi1) * tanh_f(pg1);
            float hn0 = sigm(po0) * tanh_f(c0s);
            float hn1 = sigm(po1) * tanh_f(c1s);
            union { _Float16 f; unsigned short u; } cv0, cv1;
            cv0.f = (_Float16)hn0; cv1.f = (_Float16)hn1;
            unsigned int tag = (unsigned)(t + 1) << 16;
            unsigned long long qv = (unsigned long long)(tag | cv0.u)
                                  | ((unsigned long long)(tag | cv1.u) << 32);
            unsigned long long* hd = hws + (size_t)((t + 1) & 1) * 16384
                                   + (size_t)g * 2048 + (size_t)erow * 256
                                   + c * 8 + ep;
            __hip_atomic_store(hd, qv, __ATOMIC_RELAXED,
                               __HIP_MEMORY_SCOPE_AGENT);
            if (t == 1023) {
                size_t ob = (size_t)(g * 8 + erow) * 512 + c * 16 + 2 * ep;
                out[ob]     = hn0;
                out[ob + 1] = hn1;
            }
        }

        // ---- shadow x-GEMM for step t+1 (off critical path) ----
        int tn = (t < 1023) ? (t + 1) : 0;
        const _Float16* xp = XH + xrow + (size_t)tn * 512;
#pragma unroll
        for (int kk = 0; kk < 16; kk++) xf[kk] = *(const half8*)(xp + kk * 32);
        float4v ax = {0.f, 0.f, 0.f, 0.f};
#pragma unroll
        for (int kk = 0; kk < 16; kk++) {
            half8 b = *(const half8*)&Xls[w * 16 + l15][kk * 32 + quad * 8];
            ax = __builtin_amdgcn_mfma_f32_16x16x32_f16(xf[kk], b, ax, 0, 0, 0);
        }
        accx = ax;
    }
}

// ------------------------------- launcher ----------------------------------
extern "C" void kernel_launch(void* const* d_in, const int* in_sizes, int n_in,
                              void* d_out, int out_size, void* d_ws, size_t ws_size,
                              hipStream_t stream) {
    const float* X   = (const float*)d_in[0];
    const float* Whf = (const float*)d_in[1];  const float* bhf = (const float*)d_in[2];
    const float* Wxf = (const float*)d_in[3];  const float* bxf = (const float*)d_in[4];
    const float* Whi = (const float*)d_in[5];  const float* bhi = (const float*)d_in[6];
    const float* Wxi = (const float*)d_in[7];  const float* bxi = (const float*)d_in[8];
    const float* Whg = (const float*)d_in[9];  const float* bhg = (const float*)d_in[10];
    const float* Wxg = (const float*)d_in[11]; const float* bxg = (const float*)d_in[12];
    const float* Who = (const float*)d_in[13]; const float* bho = (const float*)d_in[14];
    const float* Wxo = (const float*)d_in[15]; const float* bxo = (const float*)d_in[16];

    // ws layout: [0,256KB) tagged h double buffer | [1MB,65MB) XH fp16
    if (ws_size < (size_t)68157440) return;  // need 65 MiB

    char* ws = (char*)d_ws;
    unsigned long long* hws = (unsigned long long*)ws;
    _Float16*           XH  = (_Float16*)(ws + (1 << 20));
    (void)in_sizes; (void)n_in; (void)out_size;

    hipMemsetAsync(d_ws, 0, 262144, stream);
    xcvt<<<16384, 256, 0, stream>>>(X, XH);
    lstm_rec<<<256, 256, 0, stream>>>(Whf, Whi, Whg, Who, Wxf, Wxi, Wxg, Wxo,
                                      bxf, bxi, bxg, bxo, bhf, bhi, bhg, bho,
                                      XH, hws, (float*)d_out);
}